// Round 1
// baseline (154.354 us; speedup 1.0000x reference)
//
#include <hip/hip_runtime.h>

typedef __bf16 bf16x8 __attribute__((ext_vector_type(8)));
typedef float f32x4 __attribute__((ext_vector_type(4)));

__device__ __forceinline__ ushort f2bf(float f) {
    union { float f; unsigned u; } v; v.f = f;
    unsigned r = v.u + 0x7FFF + ((v.u >> 16) & 1);
    return (ushort)(r >> 16);
}

__device__ __forceinline__ void async_copy16(const void* g, void* l) {
    __builtin_amdgcn_global_load_lds(
        (const __attribute__((address_space(1))) void*)g,
        (__attribute__((address_space(3))) void*)l, 16, 0, 0);
}

// ---------------- cvt: x -> bf16, [Wq;Wk] -> bf16, [bq;bk] -> f32 concat ----
__global__ __launch_bounds__(256) void cvt_kernel(
    const float4* __restrict__ x, const float4* __restrict__ Wq,
    const float4* __restrict__ Wk, const float4* __restrict__ bq,
    const float4* __restrict__ bk,
    ushort4* __restrict__ xb, ushort4* __restrict__ Wb,
    float4* __restrict__ biasc) {
    int i = blockIdx.x * 256 + threadIdx.x;
    if (i < 2097152) {
        float4 v = x[i];
        ushort4 r; r.x = f2bf(v.x); r.y = f2bf(v.y); r.z = f2bf(v.z); r.w = f2bf(v.w);
        xb[i] = r;
    }
    if (i < 131072) {
        float4 v = (i < 65536) ? Wq[i] : Wk[i - 65536];
        ushort4 r; r.x = f2bf(v.x); r.y = f2bf(v.y); r.z = f2bf(v.z); r.w = f2bf(v.w);
        Wb[i] = r;
    }
    if (i < 256) {
        biasc[i] = (i < 128) ? bq[i] : bk[i - 128];
    }
}

// ---------------- fold: xzT[b][d][n] = bf16(x[b][n][d] / Z[b][n]) ----------
__global__ __launch_bounds__(256) void fold_kernel(
    const float* __restrict__ x, const float* __restrict__ Z,
    ushort* __restrict__ xzT) {
    __shared__ float tile[64][65];
    __shared__ float zin[64];
    const int b = blockIdx.y;
    const int td = blockIdx.x & 7;    // d-tile (512/64 = 8)
    const int tn = blockIdx.x >> 3;   // n-tile (2048/64 = 32)
    const int n0 = tn * 64, d0 = td * 64;
    const int t = threadIdx.x;
    if (t < 64) zin[t] = 1.0f / Z[b * 2048 + n0 + t];
    __syncthreads();
    const int c = t & 63, r0 = t >> 6;
#pragma unroll
    for (int j = 0; j < 16; ++j) {
        int r = r0 + j * 4;
        tile[r][c] = x[((size_t)b * 2048 + n0 + r) * 512 + d0 + c] * zin[r];
    }
    __syncthreads();
#pragma unroll
    for (int j = 0; j < 16; ++j) {
        int dr = r0 + j * 4;
        xzT[((size_t)b * 512 + d0 + dr) * 2048 + n0 + c] = f2bf(tile[c][dr]);
    }
}

// ---------------- bt-GEMM: C[m,n] = sum_k A[m,k]*B[n,k]  (both row-major-K) -
// EPI 0: += bias[n], store bf16          (projections)
// EPI 1: exp(acc*scale), store bf16, column-sum -> atomicAdd Z[n]  (E-pass)
// EPI 2: store fp32                       (output)
template <int EPI>
__global__ __launch_bounds__(256) void gemm_bt(
    const ushort* __restrict__ A, int lda, long sA,
    const ushort* __restrict__ B, int ldb, long sB,
    void* __restrict__ C, int ldc, long sC,
    int M, int N, int K,
    const float* __restrict__ bias, float scale,
    float* __restrict__ Z, long sZ) {
    __shared__ ushort lA[128 * 64];  // 16 KB
    __shared__ ushort lB[128 * 64];  // 16 KB
    const int b = blockIdx.y;
    A += (size_t)b * sA;
    B += (size_t)b * sB;
    const int tiles_n = N >> 7;
    const int tm = blockIdx.x / tiles_n, tn = blockIdx.x % tiles_n;
    const int t = threadIdx.x;
    const int l = t & 63, w = t >> 6;
    const int wr = w >> 1, wc = w & 1;  // 2x2 waves, each 64x64

    f32x4 acc[4][4];
#pragma unroll
    for (int i = 0; i < 4; ++i)
#pragma unroll
        for (int j = 0; j < 4; ++j) acc[i][j] = (f32x4){0.f, 0.f, 0.f, 0.f};

    for (int k0 = 0; k0 < K; k0 += 64) {
        // stage A,B tiles [128 rows][64 k] bf16 into LDS (linear dest,
        // pre-swizzled global source: LDS[row][kb] holds global kbyte kb^((row&7)<<4))
#pragma unroll
        for (int p = 0; p < 4; ++p) {
            int off = p * 4096 + t * 16;  // byte offset in 16KB tile
            int row = off >> 7;
            int kb = off & 127;
            int kswz = kb ^ ((row & 7) << 4);
            const ushort* srcA = A + (size_t)(tm * 128 + row) * lda + k0 + (kswz >> 1);
            async_copy16(srcA, (char*)lA + off);
            const ushort* srcB = B + (size_t)(tn * 128 + row) * ldb + k0 + (kswz >> 1);
            async_copy16(srcB, (char*)lB + off);
        }
        __syncthreads();
#pragma unroll
        for (int ks = 0; ks < 2; ++ks) {
            bf16x8 af[4], bfr[4];
#pragma unroll
            for (int i = 0; i < 4; ++i) {
                int row = wr * 64 + i * 16 + (l & 15);
                int colb = (ks * 64 + (l >> 4) * 16) ^ ((row & 7) << 4);
                af[i] = *(const bf16x8*)((const char*)lA + row * 128 + colb);
            }
#pragma unroll
            for (int j = 0; j < 4; ++j) {
                int row = wc * 64 + j * 16 + (l & 15);
                int colb = (ks * 64 + (l >> 4) * 16) ^ ((row & 7) << 4);
                bfr[j] = *(const bf16x8*)((const char*)lB + row * 128 + colb);
            }
#pragma unroll
            for (int i = 0; i < 4; ++i)
#pragma unroll
                for (int j = 0; j < 4; ++j)
                    acc[i][j] = __builtin_amdgcn_mfma_f32_16x16x32_bf16(
                        af[i], bfr[j], acc[i][j], 0, 0, 0);
        }
        __syncthreads();
    }

    const int m_base = tm * 128 + wr * 64;
    const int n_base = tn * 128 + wc * 64;

    if (EPI == 0) {
        ushort* Cp = (ushort*)C + (size_t)b * sC;
#pragma unroll
        for (int i = 0; i < 4; ++i)
#pragma unroll
            for (int j = 0; j < 4; ++j)
#pragma unroll
                for (int q = 0; q < 4; ++q) {
                    int row = m_base + i * 16 + (l >> 4) * 4 + q;
                    int col = n_base + j * 16 + (l & 15);
                    Cp[(size_t)row * ldc + col] = f2bf(acc[i][j][q] + bias[col]);
                }
    } else if (EPI == 1) {
        ushort* Cp = (ushort*)C + (size_t)b * sC;
        float colsum[4] = {0.f, 0.f, 0.f, 0.f};
#pragma unroll
        for (int i = 0; i < 4; ++i)
#pragma unroll
            for (int j = 0; j < 4; ++j)
#pragma unroll
                for (int q = 0; q < 4; ++q) {
                    int row = m_base + i * 16 + (l >> 4) * 4 + q;
                    int col = n_base + j * 16 + (l & 15);
                    float e = __expf(acc[i][j][q] * scale);
                    Cp[(size_t)row * ldc + col] = f2bf(e);
                    colsum[j] += e;
                }
#pragma unroll
        for (int j = 0; j < 4; ++j) {
            float s = colsum[j];
            s += __shfl_xor(s, 16);
            s += __shfl_xor(s, 32);
            if (l < 16) atomicAdd(&Z[b * sZ + n_base + j * 16 + l], s);
        }
    } else {
        float* Cp = (float*)C + (size_t)b * sC;
#pragma unroll
        for (int i = 0; i < 4; ++i)
#pragma unroll
            for (int j = 0; j < 4; ++j)
#pragma unroll
                for (int q = 0; q < 4; ++q) {
                    int row = m_base + i * 16 + (l >> 4) * 4 + q;
                    int col = n_base + j * 16 + (l & 15);
                    Cp[(size_t)row * ldc + col] = acc[i][j][q];
                }
    }
}

extern "C" void kernel_launch(void* const* d_in, const int* in_sizes, int n_in,
                              void* d_out, int out_size, void* d_ws, size_t ws_size,
                              hipStream_t stream) {
    const float* x  = (const float*)d_in[0];
    const float* Wq = (const float*)d_in[1];
    const float* bq = (const float*)d_in[2];
    const float* Wk = (const float*)d_in[3];
    const float* bk = (const float*)d_in[4];

    char* ws = (char*)d_ws;
    // layout (bytes): xb/xzT 16MB | Wb 1MB | biasc 4KB | Z 64KB | qkb 32MB | E 64MB
    ushort* xb    = (ushort*)(ws);                 // 16,777,216 (reused as xzT)
    ushort* Wb    = (ushort*)(ws + 16777216);      //  1,048,576
    float*  biasc = (float*) (ws + 17825792);      //      4,096
    float*  Z     = (float*) (ws + 17829888);      //     65,536
    ushort* qkb   = (ushort*)(ws + 17895424);      // 33,554,432
    ushort* E     = (ushort*)(ws + 51449856);      // 67,108,864  (ends ~118.6MB)
    ushort* xzT   = xb;

    hipMemsetAsync(Z, 0, 16384 * 4, stream);

    cvt_kernel<<<8192, 256, 0, stream>>>(
        (const float4*)x, (const float4*)Wq, (const float4*)Wk,
        (const float4*)bq, (const float4*)bk,
        (ushort4*)xb, (ushort4*)Wb, (float4*)biasc);

    // proj: qk[m, 0:1024] = x[m,:] . W[h,:] + bias   (M=16384, N=1024, K=512)
    gemm_bt<0><<<dim3(1024, 1), 256, 0, stream>>>(
        xb, 512, 0L, Wb, 512, 0L, qkb, 1024, 0L,
        16384, 1024, 512, biasc, 0.f, nullptr, 0L);

    // E-pass: E[b][m][n] = exp(scale * k[m].q[n]); Z[b][n] += column sums
    gemm_bt<1><<<dim3(256, 8), 256, 0, stream>>>(
        qkb + 512, 1024, 2048L * 1024, qkb, 1024, 2048L * 1024,
        E, 2048, 2048L * 2048, 2048, 2048, 512,
        nullptr, 0.04419417382415922f, Z, 2048L);

    // fold: xzT[b][d][n] = bf16(x[b][n][d] / Z[b][n])
    fold_kernel<<<dim3(256, 8), 256, 0, stream>>>(x, Z, xzT);

    // out: out[b][m][d] = sum_n E[b][m][n] * xzT[b][d][n]   (fp32 store)
    gemm_bt<2><<<dim3(64, 8), 256, 0, stream>>>(
        E, 2048, 2048L * 2048, xzT, 2048, 512L * 2048,
        d_out, 512, 2048L * 512, 2048, 512, 2048,
        nullptr, 0.f, nullptr, 0L);
}